// Round 1
// baseline (1087.713 us; speedup 1.0000x reference)
//
#include <hip/hip_runtime.h>
#include <stdint.h>

// Problem dims (fixed)
#define BB 64
#define TT 32
#define EE 512
#define HH 512
#define VV 32000
// 4*H
#define G4 2048

typedef __bf16 bf16x8 __attribute__((ext_vector_type(8)));
typedef float f32x4 __attribute__((ext_vector_type(4)));

__device__ __forceinline__ unsigned short f2bf(float f) {
  unsigned int u = __builtin_bit_cast(unsigned int, f);
  u += 0x7FFFu + ((u >> 16) & 1u);   // RNE
  return (unsigned short)(u >> 16);
}

// ---------------------------------------------------------------------------
// Kernel 1: gather [features; emb[captions]] into Xin (2112 x 512) f32
// row r<64: features[r]; else r=64+t*64+b -> emb[captions[b*T+t]]
// ---------------------------------------------------------------------------
__global__ __launch_bounds__(128) void k_embed(const float* __restrict__ feat,
                                               const int* __restrict__ cap,
                                               const float* __restrict__ emb,
                                               float* __restrict__ Xin) {
  int r = blockIdx.x;  // 0..2111
  const float* src;
  if (r < BB) {
    src = feat + (size_t)r * EE;
  } else {
    int idx = r - BB;
    int t = idx >> 6, b = idx & 63;
    src = emb + (size_t)cap[b * TT + t] * EE;
  }
  ((float4*)(Xin + (size_t)r * EE))[threadIdx.x] = ((const float4*)src)[threadIdx.x];
}

// ---------------------------------------------------------------------------
// Kernel 2: Gpre(2112 x 2048) = Xin @ W_ih.T + (b_ih + b_hh)   [fp32]
// 128x128 tile, BK=16, 256 thr, 8x8 per thread, k-major LDS tiles.
// ---------------------------------------------------------------------------
__global__ __launch_bounds__(256) void k_gemm_ih(const float* __restrict__ A,
                                                 const float* __restrict__ Bw,
                                                 const float* __restrict__ bih,
                                                 const float* __restrict__ bhh,
                                                 float* __restrict__ C) {
  __shared__ float As[16][128];
  __shared__ float Bs[16][128];
  const int tid = threadIdx.x;
  const int bx = blockIdx.x & 15;   // n tile 0..15
  const int by = blockIdx.x >> 4;   // m tile 0..16
  const int m0 = by * 128, n0 = bx * 128;
  const int tx = tid & 15, ty = tid >> 4;

  float acc[8][8];
#pragma unroll
  for (int i = 0; i < 8; i++)
#pragma unroll
    for (int j = 0; j < 8; j++) acc[i][j] = 0.f;

  const int lr = tid >> 1;           // row-in-tile 0..127
  const int lk = (tid & 1) * 8;      // 0 or 8
  int arow = m0 + lr; if (arow > 2111) arow = 2111;  // clamp (store guarded)
  const int brow = n0 + lr;          // < 2048 always
  const float* Ap = A + (size_t)arow * EE + lk;
  const float* Bp = Bw + (size_t)brow * EE + lk;

  for (int k0 = 0; k0 < EE; k0 += 16) {
    float4 a0 = *(const float4*)(Ap + k0);
    float4 a1 = *(const float4*)(Ap + k0 + 4);
    float4 b0 = *(const float4*)(Bp + k0);
    float4 b1 = *(const float4*)(Bp + k0 + 4);
    __syncthreads();
    As[lk + 0][lr] = a0.x; As[lk + 1][lr] = a0.y; As[lk + 2][lr] = a0.z; As[lk + 3][lr] = a0.w;
    As[lk + 4][lr] = a1.x; As[lk + 5][lr] = a1.y; As[lk + 6][lr] = a1.z; As[lk + 7][lr] = a1.w;
    Bs[lk + 0][lr] = b0.x; Bs[lk + 1][lr] = b0.y; Bs[lk + 2][lr] = b0.z; Bs[lk + 3][lr] = b0.w;
    Bs[lk + 4][lr] = b1.x; Bs[lk + 5][lr] = b1.y; Bs[lk + 6][lr] = b1.z; Bs[lk + 7][lr] = b1.w;
    __syncthreads();
#pragma unroll
    for (int k = 0; k < 16; k++) {
      float a[8], b[8];
      *(float4*)&a[0] = *(const float4*)&As[k][ty * 8];
      *(float4*)&a[4] = *(const float4*)&As[k][ty * 8 + 4];
      *(float4*)&b[0] = *(const float4*)&Bs[k][tx * 8];
      *(float4*)&b[4] = *(const float4*)&Bs[k][tx * 8 + 4];
#pragma unroll
      for (int i = 0; i < 8; i++)
#pragma unroll
        for (int j = 0; j < 8; j++) acc[i][j] += a[i] * b[j];
    }
  }

  float bs[8];
#pragma unroll
  for (int j = 0; j < 8; j++) {
    int n = n0 + tx * 8 + j;
    bs[j] = bih[n] + bhh[n];
  }
#pragma unroll
  for (int i = 0; i < 8; i++) {
    int m = m0 + ty * 8 + i;
    if (m < 2112) {
      float4 o0, o1;
      o0.x = acc[i][0] + bs[0]; o0.y = acc[i][1] + bs[1];
      o0.z = acc[i][2] + bs[2]; o0.w = acc[i][3] + bs[3];
      o1.x = acc[i][4] + bs[4]; o1.y = acc[i][5] + bs[5];
      o1.z = acc[i][6] + bs[6]; o1.w = acc[i][7] + bs[7];
      *(float4*)(C + (size_t)m * G4 + n0 + tx * 8) = o0;
      *(float4*)(C + (size_t)m * G4 + n0 + tx * 8 + 4) = o1;
    }
  }
}

// ---------------------------------------------------------------------------
// Kernel 3: one LSTM step.  grid 256 x 128thr; u = bid*2 + (tid>>6) (wave-
// uniform -> scalar W_hh loads), b = tid&63.  gates = Gpre[s*64+b] + h@W_hh.T
// PyTorch gate order i,f,g,o = rows u, 512+u, 1024+u, 1536+u of W.
// h double-buffered across steps (race-free); c owner-computed in place.
// ---------------------------------------------------------------------------
template <bool PRIME>
__global__ __launch_bounds__(128) void k_step(const float* __restrict__ Gpre,
                                              const float* __restrict__ Whh,
                                              const float* __restrict__ hin,
                                              float* __restrict__ hout,
                                              float* __restrict__ c,
                                              unsigned short* __restrict__ hall,
                                              int s) {
  const int tid = threadIdx.x;
  const int b = tid & 63;
  int u = blockIdx.x * 2 + (tid >> 6);
  u = __builtin_amdgcn_readfirstlane(u);

  const float* gp = Gpre + ((size_t)(s * 64 + b)) * G4 + u;
  float gi = gp[0], gf = gp[512], gg = gp[1024], go = gp[1536];

  if (!PRIME) {
    const float4* h4 = (const float4*)(hin + (size_t)b * HH);
    const float4* wi4 = (const float4*)(Whh + (size_t)(0 * HH + u) * HH);
    const float4* wf4 = (const float4*)(Whh + (size_t)(1 * HH + u) * HH);
    const float4* wg4 = (const float4*)(Whh + (size_t)(2 * HH + u) * HH);
    const float4* wo4 = (const float4*)(Whh + (size_t)(3 * HH + u) * HH);
    float ai = 0.f, af = 0.f, ag = 0.f, ao = 0.f;
#pragma unroll 4
    for (int k = 0; k < HH / 4; k++) {
      float4 hv = h4[k];
      float4 wi = wi4[k], wf = wf4[k], wg = wg4[k], wo = wo4[k];
      ai += hv.x * wi.x + hv.y * wi.y + hv.z * wi.z + hv.w * wi.w;
      af += hv.x * wf.x + hv.y * wf.y + hv.z * wf.z + hv.w * wf.w;
      ag += hv.x * wg.x + hv.y * wg.y + hv.z * wg.z + hv.w * wg.w;
      ao += hv.x * wo.x + hv.y * wo.y + hv.z * wo.z + hv.w * wo.w;
    }
    gi += ai; gf += af; gg += ag; go += ao;
  }

  float cold = PRIME ? 0.f : c[(size_t)b * HH + u];
  float ig = 1.f / (1.f + __expf(-gi));
  float fg = 1.f / (1.f + __expf(-gf));
  float og = 1.f / (1.f + __expf(-go));
  float gt = tanhf(gg);
  float cn = fg * cold + ig * gt;
  float hn = og * tanhf(cn);
  c[(size_t)b * HH + u] = cn;
  hout[(size_t)b * HH + u] = hn;
  if (!PRIME) hall[((size_t)(s - 1) * 64 + b) * HH + u] = f2bf(hn);
}

// ---------------------------------------------------------------------------
// Kernel 4: cast W_out f32 -> bf16 (ushort)
// ---------------------------------------------------------------------------
__global__ void k_cast(const float* __restrict__ src, unsigned short* __restrict__ dst, int n4) {
  int i = blockIdx.x * blockDim.x + threadIdx.x;
  int stride = gridDim.x * blockDim.x;
  for (; i < n4; i += stride) {
    float4 v = ((const float4*)src)[i];
    ushort4 o;
    o.x = f2bf(v.x); o.y = f2bf(v.y); o.z = f2bf(v.z); o.w = f2bf(v.w);
    ((ushort4*)dst)[i] = o;
  }
}

// ---------------------------------------------------------------------------
// Kernel 5: Out(2048 x 32000) = h_all @ W_out.T + b_out  [bf16 MFMA, f32 out]
// 128x128 tile, BK=64, 256 thr / 4 waves (2x2), 16x16x32 MFMA.
// Reg-staged LDS with T2-style 16B-chunk XOR swizzle (write & read both
// swizzled -> conflict-free ds_read_b128).  Row r=t*64+b of the GEMM maps to
// out[b][t][:]. XCD-aware bijective block swizzle (4000 % 8 == 0).
// ---------------------------------------------------------------------------
__global__ __launch_bounds__(256) void k_gemm_out(const unsigned short* __restrict__ Xb,
                                                  const unsigned short* __restrict__ Wb,
                                                  const float* __restrict__ bout,
                                                  float* __restrict__ out) {
  __shared__ __align__(16) unsigned short As[128 * 64];
  __shared__ __align__(16) unsigned short Bs[128 * 64];
  const int tid = threadIdx.x;
  int bid = blockIdx.x;
  int swz = (bid & 7) * 500 + (bid >> 3);  // 8 XCDs, 4000 blocks
  const int mt = swz & 15;   // 16 m-tiles (col-major tile order for L2 reuse)
  const int nt = swz >> 4;   // 250 n-tiles
  const int l = tid & 63;
  const int w = tid >> 6;
  const int wr = (w >> 1) * 64;
  const int wc = (w & 1) * 64;

  const f32x4 vzero = {0.f, 0.f, 0.f, 0.f};
  f32x4 acc[4][4];
#pragma unroll
  for (int m = 0; m < 4; m++)
#pragma unroll
    for (int n = 0; n < 4; n++) acc[m][n] = vzero;

  const size_t a_base = (size_t)(mt * 128) * EE;
  const size_t b_base = (size_t)(nt * 128) * EE;

  for (int kt = 0; kt < EE / 64; kt++) {
    int4 av[4], bv[4];
#pragma unroll
    for (int i = 0; i < 4; i++) {
      int beta = i * 4096 + tid * 16;    // byte offset in 16KB tile
      int row = beta >> 7;               // 128B per row (64 bf16)
      int cb = (beta >> 4) & 7;          // 16B chunk in row
      av[i] = *(const int4*)(Xb + a_base + (size_t)row * EE + kt * 64 + cb * 8);
      bv[i] = *(const int4*)(Wb + b_base + (size_t)row * EE + kt * 64 + cb * 8);
    }
    __syncthreads();  // previous iteration's reads done
#pragma unroll
    for (int i = 0; i < 4; i++) {
      int beta = i * 4096 + tid * 16;
      int row = beta >> 7;
      int cb = (beta >> 4) & 7;
      int cs = cb ^ (row & 7);           // T2 swizzle
      *(int4*)&As[row * 64 + cs * 8] = av[i];
      *(int4*)&Bs[row * 64 + cs * 8] = bv[i];
    }
    __syncthreads();
#pragma unroll
    for (int kk = 0; kk < 2; kk++) {
      bf16x8 af[4], bfr[4];
#pragma unroll
      for (int m = 0; m < 4; m++) {
        int row = wr + m * 16 + (l & 15);
        int cc = kk * 4 + (l >> 4);
        int cs = cc ^ (row & 7);
        af[m] = *(const bf16x8*)&As[row * 64 + cs * 8];
      }
#pragma unroll
      for (int n = 0; n < 4; n++) {
        int row = wc + n * 16 + (l & 15);
        int cc = kk * 4 + (l >> 4);
        int cs = cc ^ (row & 7);
        bfr[n] = *(const bf16x8*)&Bs[row * 64 + cs * 8];
      }
#pragma unroll
      for (int m = 0; m < 4; m++)
#pragma unroll
        for (int n = 0; n < 4; n++)
          acc[m][n] = __builtin_amdgcn_mfma_f32_16x16x32_bf16(af[m], bfr[n], acc[m][n], 0, 0, 0);
    }
  }

  // epilogue: C/D layout col = lane&15, row = (lane>>4)*4 + j   [m89]
#pragma unroll
  for (int n = 0; n < 4; n++) {
    int col = nt * 128 + wc + n * 16 + (l & 15);
    float bo = bout[col];
#pragma unroll
    for (int m = 0; m < 4; m++) {
#pragma unroll
      for (int j = 0; j < 4; j++) {
        int r = mt * 128 + wr + m * 16 + (l >> 4) * 4 + j;
        int t = r >> 6, b = r & 63;
        out[((size_t)(b * TT + t)) * VV + col] = acc[m][n][j] + bo;
      }
    }
  }
}

// ---------------------------------------------------------------------------
extern "C" void kernel_launch(void* const* d_in, const int* in_sizes, int n_in,
                              void* d_out, int out_size, void* d_ws, size_t ws_size,
                              hipStream_t stream) {
  const float* feat = (const float*)d_in[0];
  const int* cap = (const int*)d_in[1];
  // d_in[2] = seq_len (constant 32)
  const float* emb = (const float*)d_in[3];
  const float* Wih = (const float*)d_in[4];
  const float* Whh = (const float*)d_in[5];
  const float* bih = (const float*)d_in[6];
  const float* bhh = (const float*)d_in[7];
  const float* Wout = (const float*)d_in[8];
  const float* bout = (const float*)d_in[9];
  float* out = (float*)d_out;

  char* ws = (char*)d_ws;
  float* Xin = (float*)ws;                                  //  4,325,376 B
  float* Gpre = (float*)(ws + 4325376);                     // 17,301,504 B
  float* h0 = (float*)(ws + 21626880);                      //    131,072 B
  float* h1 = (float*)(ws + 21757952);                      //    131,072 B
  float* cbuf = (float*)(ws + 21889024);                    //    131,072 B
  unsigned short* hall = (unsigned short*)(ws + 22020096);  //  2,097,152 B
  unsigned short* Wb = (unsigned short*)(ws + 24117248);    // 32,768,000 B -> 56.9MB total

  k_embed<<<dim3(2112), dim3(128), 0, stream>>>(feat, cap, emb, Xin);
  k_gemm_ih<<<dim3(17 * 16), dim3(256), 0, stream>>>(Xin, Wih, bih, bhh, Gpre);
  k_cast<<<dim3(2048), dim3(256), 0, stream>>>(Wout, Wb, (VV * EE) / 4);

  // priming step (h=c=0), writes h1
  k_step<true><<<dim3(256), dim3(128), 0, stream>>>(Gpre, Whh, h0, h1, cbuf, hall, 0);
  for (int s = 1; s <= TT; s++) {
    float* hin = (s & 1) ? h1 : h0;
    float* hout_ = (s & 1) ? h0 : h1;
    k_step<false><<<dim3(256), dim3(128), 0, stream>>>(Gpre, Whh, hin, hout_, cbuf, hall, s);
  }

  k_gemm_out<<<dim3(4000), dim3(256), 0, stream>>>(hall, Wb, bout, out);
}

// Round 2
// 922.009 us; speedup vs baseline: 1.1797x; 1.1797x over previous
//
#include <hip/hip_runtime.h>
#include <stdint.h>

// Problem dims (fixed)
#define BB 64
#define TT 32
#define EE 512
#define HH 512
#define VV 32000
#define G4 2048

typedef __bf16 bf16x8 __attribute__((ext_vector_type(8)));
typedef float f32x4 __attribute__((ext_vector_type(4)));

__device__ __forceinline__ unsigned short f2bf(float f) {
  unsigned int u = __builtin_bit_cast(unsigned int, f);
  u += 0x7FFFu + ((u >> 16) & 1u);   // RNE
  return (unsigned short)(u >> 16);
}
__device__ __forceinline__ float bf2f(unsigned short h) {
  unsigned int u = ((unsigned int)h) << 16;
  return __builtin_bit_cast(float, u);
}
__device__ __forceinline__ void gload_lds16(const unsigned short* g, unsigned short* l) {
  __builtin_amdgcn_global_load_lds((const __attribute__((address_space(1))) void*)g,
                                   (__attribute__((address_space(3))) void*)l, 16, 0, 0);
}

// ---------------------------------------------------------------------------
// Kernel 1: Gpre(2112 x 2048) = [feat; emb[cap]] @ W_ih.T + (b_ih + b_hh) [fp32]
// 128x128 tile, BK=16, 256 thr, 8x8/thread. Embedding gather fused into the
// A-row pointer (each thread owns one A row for the whole K loop).
// ---------------------------------------------------------------------------
__global__ __launch_bounds__(256) void k_gemm_ih(const float* __restrict__ feat,
                                                 const int* __restrict__ cap,
                                                 const float* __restrict__ emb,
                                                 const float* __restrict__ Bw,
                                                 const float* __restrict__ bih,
                                                 const float* __restrict__ bhh,
                                                 float* __restrict__ C) {
  __shared__ float As[16][128];
  __shared__ float Bs[16][128];
  const int tid = threadIdx.x;
  const int bx = blockIdx.x & 15;   // n tile 0..15
  const int by = blockIdx.x >> 4;   // m tile 0..16
  const int m0 = by * 128, n0 = bx * 128;
  const int tx = tid & 15, ty = tid >> 4;

  float acc[8][8];
#pragma unroll
  for (int i = 0; i < 8; i++)
#pragma unroll
    for (int j = 0; j < 8; j++) acc[i][j] = 0.f;

  const int lr = tid >> 1;           // row-in-tile 0..127
  const int lk = (tid & 1) * 8;      // 0 or 8
  int arow = m0 + lr; if (arow > 2111) arow = 2111;  // clamp (store guarded)
  const float* Ap;
  if (arow < BB) {
    Ap = feat + (size_t)arow * EE + lk;
  } else {
    int idx = arow - BB;
    int t = idx >> 6, b = idx & 63;
    Ap = emb + (size_t)cap[b * TT + t] * EE + lk;
  }
  const int brow = n0 + lr;          // < 2048 always
  const float* Bp = Bw + (size_t)brow * EE + lk;

  for (int k0 = 0; k0 < EE; k0 += 16) {
    float4 a0 = *(const float4*)(Ap + k0);
    float4 a1 = *(const float4*)(Ap + k0 + 4);
    float4 b0 = *(const float4*)(Bp + k0);
    float4 b1 = *(const float4*)(Bp + k0 + 4);
    __syncthreads();
    As[lk + 0][lr] = a0.x; As[lk + 1][lr] = a0.y; As[lk + 2][lr] = a0.z; As[lk + 3][lr] = a0.w;
    As[lk + 4][lr] = a1.x; As[lk + 5][lr] = a1.y; As[lk + 6][lr] = a1.z; As[lk + 7][lr] = a1.w;
    Bs[lk + 0][lr] = b0.x; Bs[lk + 1][lr] = b0.y; Bs[lk + 2][lr] = b0.z; Bs[lk + 3][lr] = b0.w;
    Bs[lk + 4][lr] = b1.x; Bs[lk + 5][lr] = b1.y; Bs[lk + 6][lr] = b1.z; Bs[lk + 7][lr] = b1.w;
    __syncthreads();
#pragma unroll
    for (int k = 0; k < 16; k++) {
      float a[8], b[8];
      *(float4*)&a[0] = *(const float4*)&As[k][ty * 8];
      *(float4*)&a[4] = *(const float4*)&As[k][ty * 8 + 4];
      *(float4*)&b[0] = *(const float4*)&Bs[k][tx * 8];
      *(float4*)&b[4] = *(const float4*)&Bs[k][tx * 8 + 4];
#pragma unroll
      for (int i = 0; i < 8; i++)
#pragma unroll
        for (int j = 0; j < 8; j++) acc[i][j] += a[i] * b[j];
    }
  }

  float bs[8];
#pragma unroll
  for (int j = 0; j < 8; j++) {
    int n = n0 + tx * 8 + j;
    bs[j] = bih[n] + bhh[n];
  }
#pragma unroll
  for (int i = 0; i < 8; i++) {
    int m = m0 + ty * 8 + i;
    if (m < 2112) {
      float4 o0, o1;
      o0.x = acc[i][0] + bs[0]; o0.y = acc[i][1] + bs[1];
      o0.z = acc[i][2] + bs[2]; o0.w = acc[i][3] + bs[3];
      o1.x = acc[i][4] + bs[4]; o1.y = acc[i][5] + bs[5];
      o1.z = acc[i][6] + bs[6]; o1.w = acc[i][7] + bs[7];
      *(float4*)(C + (size_t)m * G4 + n0 + tx * 8) = o0;
      *(float4*)(C + (size_t)m * G4 + n0 + tx * 8 + 4) = o1;
    }
  }
}

// ---------------------------------------------------------------------------
// Kernel 2: cast W_out f32 -> bf16
// ---------------------------------------------------------------------------
__global__ void k_cast(const float* __restrict__ src, unsigned short* __restrict__ dst, int n4) {
  int i = blockIdx.x * blockDim.x + threadIdx.x;
  int stride = gridDim.x * blockDim.x;
  for (; i < n4; i += stride) {
    float4 v = ((const float4*)src)[i];
    ushort4 o;
    o.x = f2bf(v.x); o.y = f2bf(v.y); o.z = f2bf(v.z); o.w = f2bf(v.w);
    ((ushort4*)dst)[i] = o;
  }
}

// ---------------------------------------------------------------------------
// Kernel 3: split W_hh f32 -> (hi, lo) bf16 pair.  hi = rne(v); lo = rne(v-hi)
// ---------------------------------------------------------------------------
__global__ void k_split(const float* __restrict__ src, unsigned short* __restrict__ hi,
                        unsigned short* __restrict__ lo, int n4) {
  int i = blockIdx.x * blockDim.x + threadIdx.x;
  int stride = gridDim.x * blockDim.x;
  for (; i < n4; i += stride) {
    float4 v = ((const float4*)src)[i];
    ushort4 h, l;
    h.x = f2bf(v.x); l.x = f2bf(v.x - bf2f(h.x));
    h.y = f2bf(v.y); l.y = f2bf(v.y - bf2f(h.y));
    h.z = f2bf(v.z); l.z = f2bf(v.z - bf2f(h.z));
    h.w = f2bf(v.w); l.w = f2bf(v.w - bf2f(h.w));
    ((ushort4*)hi)[i] = h;
    ((ushort4*)lo)[i] = l;
  }
}

// ---------------------------------------------------------------------------
// Kernel 4: priming LSTM step (h=c=0): pure elementwise from Gpre rows 0..63.
// ---------------------------------------------------------------------------
__global__ __launch_bounds__(256) void k_prime(const float* __restrict__ Gpre,
                                               unsigned short* __restrict__ hhi,
                                               unsigned short* __restrict__ hlo,
                                               float* __restrict__ c) {
  int i = blockIdx.x * 256 + threadIdx.x;  // 0..32767
  int b = i >> 9, u = i & 511;
  const float* gp = Gpre + (size_t)b * G4;
  float gi = gp[u], gf = gp[512 + u], gg = gp[1024 + u], go = gp[1536 + u];
  (void)gf;
  float ig = 1.f / (1.f + __expf(-gi));
  float og = 1.f / (1.f + __expf(-go));
  float cn = ig * tanhf(gg);               // c_old = 0
  float hn = og * tanhf(cn);
  c[i] = cn;
  unsigned short hb = f2bf(hn);
  hhi[i] = hb;
  hlo[i] = f2bf(hn - bf2f(hb));
}

// ---------------------------------------------------------------------------
// Kernel 5: one LSTM step via split-bf16 MFMA.
// 32 blocks x 256 thr (4 waves). Block owns u0=bid*16 (16 u x 4 gates = 64
// gate-cols). Wave w owns b-rows [w*16, w*16+16). acc[g] 16x16 tile per gate:
// col (lane&15) = u, row field = b. gates += h @ W_hh.T via 3 MFMAs
// (hi*hi + hi*lo + lo*hi); c,h owner-computed; hall stored b-major (row b*32+t).
// ---------------------------------------------------------------------------
__global__ __launch_bounds__(256) void k_step2(const float* __restrict__ Gpre,
                                               const unsigned short* __restrict__ Whi,
                                               const unsigned short* __restrict__ Wlo,
                                               const unsigned short* __restrict__ hhi_in,
                                               const unsigned short* __restrict__ hlo_in,
                                               unsigned short* __restrict__ hhi_out,
                                               unsigned short* __restrict__ hlo_out,
                                               float* __restrict__ c,
                                               unsigned short* __restrict__ hall,
                                               int s) {
  const int tid = threadIdx.x;
  const int l = tid & 63;
  const int w = tid >> 6;
  const int u0 = blockIdx.x * 16;
  const int lr = l & 15;         // col: u-offset
  const int lk = (l >> 4) * 8;   // k-chunk base

  const f32x4 vz = {0.f, 0.f, 0.f, 0.f};
  f32x4 acc[4] = {vz, vz, vz, vz};

  const size_t a_off = (size_t)(w * 16 + lr) * HH + lk;
  size_t b_off[4];
#pragma unroll
  for (int g = 0; g < 4; g++) b_off[g] = (size_t)(g * HH + u0 + lr) * HH + lk;

  for (int k0 = 0; k0 < HH; k0 += 32) {
    bf16x8 ah = *(const bf16x8*)(hhi_in + a_off + k0);
    bf16x8 al = *(const bf16x8*)(hlo_in + a_off + k0);
#pragma unroll
    for (int g = 0; g < 4; g++) {
      bf16x8 bh = *(const bf16x8*)(Whi + b_off[g] + k0);
      bf16x8 bl = *(const bf16x8*)(Wlo + b_off[g] + k0);
      acc[g] = __builtin_amdgcn_mfma_f32_16x16x32_bf16(ah, bh, acc[g], 0, 0, 0);
      acc[g] = __builtin_amdgcn_mfma_f32_16x16x32_bf16(ah, bl, acc[g], 0, 0, 0);
      acc[g] = __builtin_amdgcn_mfma_f32_16x16x32_bf16(al, bh, acc[g], 0, 0, 0);
    }
  }

#pragma unroll
  for (int j = 0; j < 4; j++) {
    int b = w * 16 + (l >> 4) * 4 + j;
    int u = u0 + lr;
    const float* gp = Gpre + (size_t)(s * 64 + b) * G4 + u;
    float gi = acc[0][j] + gp[0];
    float gf = acc[1][j] + gp[512];
    float gg = acc[2][j] + gp[1024];
    float go = acc[3][j] + gp[1536];
    size_t cu = (size_t)b * HH + u;
    float cold = c[cu];
    float ig = 1.f / (1.f + __expf(-gi));
    float fg = 1.f / (1.f + __expf(-gf));
    float og = 1.f / (1.f + __expf(-go));
    float cn = fg * cold + ig * tanhf(gg);
    float hn = og * tanhf(cn);
    c[cu] = cn;
    unsigned short hb = f2bf(hn);
    hhi_out[cu] = hb;
    hlo_out[cu] = f2bf(hn - bf2f(hb));
    hall[((size_t)b * TT + (s - 1)) * HH + u] = hb;
  }
}

// ---------------------------------------------------------------------------
// Kernel 6: Out(2048 x 32000) = hall @ W_out.T + b_out  [bf16 MFMA, f32 out]
// 128x128 tile, BK=64, 256 thr / 4 waves (2x2), global_load_lds width-16 with
// pre-swizzled global source (linear LDS dest) + swizzled ds_read (rule 21).
// MFMA operands SWAPPED: col(lane&15) = out-row, row field = out-col -> each
// lane stores float4 of 4 consecutive cols; hall is b-major so GEMM row ==
// out row (contiguous 128-row x 512B band per block). XCD-chunked swizzle.
// ---------------------------------------------------------------------------
__global__ __launch_bounds__(256) void k_gemm_out(const unsigned short* __restrict__ Xb,
                                                  const unsigned short* __restrict__ Wb,
                                                  const float* __restrict__ bout,
                                                  float* __restrict__ out) {
  __shared__ __align__(16) unsigned short As[128 * 64];
  __shared__ __align__(16) unsigned short Bs[128 * 64];
  const int tid = threadIdx.x;
  int bid = blockIdx.x;
  int swz = (bid & 7) * 500 + (bid >> 3);  // 8 XCDs x 500-block chunks (4000%8==0)
  const int mt = swz & 15;   // 16 m-tiles, fastest -> 16 consecutive blocks share B tile
  const int nt = swz >> 4;   // 250 n-tiles
  const int l = tid & 63;
  const int w = tid >> 6;
  const int wr = (w >> 1) * 64;  // m-offset of wave
  const int wc = (w & 1) * 64;   // n-offset of wave

  const f32x4 vz = {0.f, 0.f, 0.f, 0.f};
  f32x4 acc[4][4];
#pragma unroll
  for (int m = 0; m < 4; m++)
#pragma unroll
    for (int n = 0; n < 4; n++) acc[m][n] = vz;

  // staging: thread covers (row = i*32 + tid>>3, chunk cs = tid&7); global
  // chunk fetched is cs ^ (row&7) so that swizzled ds_read sees linear data.
  const int srow = tid >> 3;   // 0..31
  const int scs = tid & 7;
  const unsigned short* ga0 = Xb + (size_t)(mt * 128) * EE;
  const unsigned short* gb0 = Wb + (size_t)(nt * 128) * EE;

  for (int kt = 0; kt < 8; kt++) {
    if (kt) __syncthreads();   // prev compute's LDS reads done before overwrite
#pragma unroll
    for (int i = 0; i < 4; i++) {
      int row = i * 32 + srow;
      int cb = scs ^ (row & 7);
      gload_lds16(ga0 + (size_t)row * EE + kt * 64 + cb * 8, &As[row * 64 + scs * 8]);
      gload_lds16(gb0 + (size_t)row * EE + kt * 64 + cb * 8, &Bs[row * 64 + scs * 8]);
    }
    __syncthreads();           // compiler drains vmcnt(0) before barrier
#pragma unroll
    for (int kk = 0; kk < 2; kk++) {
      bf16x8 af[4], bfr[4];
#pragma unroll
      for (int m = 0; m < 4; m++) {
        int row = wr + m * 16 + (l & 15);
        int cc = kk * 4 + (l >> 4);
        int cs = cc ^ (row & 7);
        af[m] = *(const bf16x8*)&As[row * 64 + cs * 8];
      }
#pragma unroll
      for (int n = 0; n < 4; n++) {
        int row = wc + n * 16 + (l & 15);
        int cc = kk * 4 + (l >> 4);
        int cs = cc ^ (row & 7);
        bfr[n] = *(const bf16x8*)&Bs[row * 64 + cs * 8];
      }
      // swapped operands: col(lane&15) <- af (A row), row-field <- bfr (W row)
#pragma unroll
      for (int m = 0; m < 4; m++)
#pragma unroll
        for (int n = 0; n < 4; n++)
          acc[m][n] = __builtin_amdgcn_mfma_f32_16x16x32_bf16(bfr[n], af[m], acc[m][n], 0, 0, 0);
    }
  }

  // epilogue: lane l holds, for (m,n), out[mt*128+wr+m*16+(l&15)]
  //                                      [nt*128+wc+n*16+(l>>4)*4 + j], j=0..3
  float4 bo4[4];
#pragma unroll
  for (int n = 0; n < 4; n++)
    bo4[n] = *(const float4*)(bout + nt * 128 + wc + n * 16 + (l >> 4) * 4);
#pragma unroll
  for (int m = 0; m < 4; m++) {
    float* orow = out + (size_t)(mt * 128 + wr + m * 16 + (l & 15)) * VV
                      + nt * 128 + wc + (l >> 4) * 4;
#pragma unroll
    for (int n = 0; n < 4; n++) {
      float4 v;
      v.x = acc[m][n][0] + bo4[n].x;
      v.y = acc[m][n][1] + bo4[n].y;
      v.z = acc[m][n][2] + bo4[n].z;
      v.w = acc[m][n][3] + bo4[n].w;
      *(float4*)(orow + n * 16) = v;
    }
  }
}

// ---------------------------------------------------------------------------
extern "C" void kernel_launch(void* const* d_in, const int* in_sizes, int n_in,
                              void* d_out, int out_size, void* d_ws, size_t ws_size,
                              hipStream_t stream) {
  const float* feat = (const float*)d_in[0];
  const int* cap = (const int*)d_in[1];
  // d_in[2] = seq_len (constant 32)
  const float* emb = (const float*)d_in[3];
  const float* Wih = (const float*)d_in[4];
  const float* Whh = (const float*)d_in[5];
  const float* bih = (const float*)d_in[6];
  const float* bhh = (const float*)d_in[7];
  const float* Wout = (const float*)d_in[8];
  const float* bout = (const float*)d_in[9];
  float* out = (float*)d_out;

  char* ws = (char*)d_ws;
  float* Gpre = (float*)ws;                                  // 17,301,504
  float* cbuf = (float*)(ws + 17301504);                     //    131,072
  unsigned short* hhi0 = (unsigned short*)(ws + 17432576);   //     65,536
  unsigned short* hhi1 = (unsigned short*)(ws + 17498112);   //     65,536
  unsigned short* hlo0 = (unsigned short*)(ws + 17563648);   //     65,536
  unsigned short* hlo1 = (unsigned short*)(ws + 17629184);   //     65,536
  unsigned short* hall = (unsigned short*)(ws + 17694720);   //  2,097,152 (b-major)
  unsigned short* Whi = (unsigned short*)(ws + 19791872);    //  2,097,152
  unsigned short* Wlo = (unsigned short*)(ws + 21889024);    //  2,097,152
  unsigned short* Wb = (unsigned short*)(ws + 23986176);     // 32,768,000 -> 56.75 MB

  k_gemm_ih<<<dim3(17 * 16), dim3(256), 0, stream>>>(feat, cap, emb, Wih, bih, bhh, Gpre);
  k_split<<<dim3(512), dim3(256), 0, stream>>>(Whh, Whi, Wlo, (G4 * HH) / 4);
  k_cast<<<dim3(2048), dim3(256), 0, stream>>>(Wout, Wb, (VV * HH) / 4);

  k_prime<<<dim3(128), dim3(256), 0, stream>>>(Gpre, hhi0, hlo0, cbuf);
  for (int s = 1; s <= TT; s++) {
    const unsigned short *hi_in, *lo_in;
    unsigned short *hi_out, *lo_out;
    if (s & 1) { hi_in = hhi0; lo_in = hlo0; hi_out = hhi1; lo_out = hlo1; }
    else       { hi_in = hhi1; lo_in = hlo1; hi_out = hhi0; lo_out = hlo0; }
    k_step2<<<dim3(32), dim3(256), 0, stream>>>(Gpre, Whi, Wlo, hi_in, lo_in,
                                                hi_out, lo_out, cbuf, hall, s);
  }

  k_gemm_out<<<dim3(4000), dim3(256), 0, stream>>>(hall, Wb, bout, out);
}

// Round 3
// 634.035 us; speedup vs baseline: 1.7155x; 1.4542x over previous
//
#include <hip/hip_runtime.h>
#include <stdint.h>

// Problem dims (fixed)
#define BB 64
#define TT 32
#define EE 512
#define HH 512
#define VV 32000
#define G4 2048

typedef __bf16 bf16x8 __attribute__((ext_vector_type(8)));
typedef float f32x4 __attribute__((ext_vector_type(4)));

__device__ __forceinline__ unsigned short f2bf(float f) {
  unsigned int u = __builtin_bit_cast(unsigned int, f);
  u += 0x7FFFu + ((u >> 16) & 1u);   // RNE
  return (unsigned short)(u >> 16);
}
__device__ __forceinline__ float bf2f(unsigned short h) {
  unsigned int u = ((unsigned int)h) << 16;
  return __builtin_bit_cast(float, u);
}
__device__ __forceinline__ void gload_lds16(const unsigned short* g, unsigned short* l) {
  __builtin_amdgcn_global_load_lds((const __attribute__((address_space(1))) void*)g,
                                   (__attribute__((address_space(3))) void*)l, 16, 0, 0);
}
__device__ __forceinline__ float sigm(float x) { return 1.f / (1.f + __expf(-x)); }
__device__ __forceinline__ float tanh_fast(float x) {
  // tanh(x) = 1 - 2/(e^{2x}+1); stable at +-inf
  return 1.f - 2.f / (__expf(2.f * x) + 1.f);
}

// ---------------------------------------------------------------------------
// Kernel 1: Gpre(2112 x 2048) = [feat; emb[cap]] @ W_ih.T + (b_ih + b_hh) [fp32]
// ---------------------------------------------------------------------------
__global__ __launch_bounds__(256) void k_gemm_ih(const float* __restrict__ feat,
                                                 const int* __restrict__ cap,
                                                 const float* __restrict__ emb,
                                                 const float* __restrict__ Bw,
                                                 const float* __restrict__ bih,
                                                 const float* __restrict__ bhh,
                                                 float* __restrict__ C) {
  __shared__ float As[16][128];
  __shared__ float Bs[16][128];
  const int tid = threadIdx.x;
  const int bx = blockIdx.x & 15;   // n tile 0..15
  const int by = blockIdx.x >> 4;   // m tile 0..16
  const int m0 = by * 128, n0 = bx * 128;
  const int tx = tid & 15, ty = tid >> 4;

  float acc[8][8];
#pragma unroll
  for (int i = 0; i < 8; i++)
#pragma unroll
    for (int j = 0; j < 8; j++) acc[i][j] = 0.f;

  const int lr = tid >> 1;           // row-in-tile 0..127
  const int lk = (tid & 1) * 8;      // 0 or 8
  int arow = m0 + lr; if (arow > 2111) arow = 2111;  // clamp (store guarded)
  const float* Ap;
  if (arow < BB) {
    Ap = feat + (size_t)arow * EE + lk;
  } else {
    int idx = arow - BB;
    int t = idx >> 6, b = idx & 63;
    Ap = emb + (size_t)cap[b * TT + t] * EE + lk;
  }
  const int brow = n0 + lr;          // < 2048 always
  const float* Bp = Bw + (size_t)brow * EE + lk;

  for (int k0 = 0; k0 < EE; k0 += 16) {
    float4 a0 = *(const float4*)(Ap + k0);
    float4 a1 = *(const float4*)(Ap + k0 + 4);
    float4 b0 = *(const float4*)(Bp + k0);
    float4 b1 = *(const float4*)(Bp + k0 + 4);
    __syncthreads();
    As[lk + 0][lr] = a0.x; As[lk + 1][lr] = a0.y; As[lk + 2][lr] = a0.z; As[lk + 3][lr] = a0.w;
    As[lk + 4][lr] = a1.x; As[lk + 5][lr] = a1.y; As[lk + 6][lr] = a1.z; As[lk + 7][lr] = a1.w;
    Bs[lk + 0][lr] = b0.x; Bs[lk + 1][lr] = b0.y; Bs[lk + 2][lr] = b0.z; Bs[lk + 3][lr] = b0.w;
    Bs[lk + 4][lr] = b1.x; Bs[lk + 5][lr] = b1.y; Bs[lk + 6][lr] = b1.z; Bs[lk + 7][lr] = b1.w;
    __syncthreads();
#pragma unroll
    for (int k = 0; k < 16; k++) {
      float a[8], b[8];
      *(float4*)&a[0] = *(const float4*)&As[k][ty * 8];
      *(float4*)&a[4] = *(const float4*)&As[k][ty * 8 + 4];
      *(float4*)&b[0] = *(const float4*)&Bs[k][tx * 8];
      *(float4*)&b[4] = *(const float4*)&Bs[k][tx * 8 + 4];
#pragma unroll
      for (int i = 0; i < 8; i++)
#pragma unroll
        for (int j = 0; j < 8; j++) acc[i][j] += a[i] * b[j];
    }
  }

  float bs[8];
#pragma unroll
  for (int j = 0; j < 8; j++) {
    int n = n0 + tx * 8 + j;
    bs[j] = bih[n] + bhh[n];
  }
#pragma unroll
  for (int i = 0; i < 8; i++) {
    int m = m0 + ty * 8 + i;
    if (m < 2112) {
      float4 o0, o1;
      o0.x = acc[i][0] + bs[0]; o0.y = acc[i][1] + bs[1];
      o0.z = acc[i][2] + bs[2]; o0.w = acc[i][3] + bs[3];
      o1.x = acc[i][4] + bs[4]; o1.y = acc[i][5] + bs[5];
      o1.z = acc[i][6] + bs[6]; o1.w = acc[i][7] + bs[7];
      *(float4*)(C + (size_t)m * G4 + n0 + tx * 8) = o0;
      *(float4*)(C + (size_t)m * G4 + n0 + tx * 8 + 4) = o1;
    }
  }
}

// ---------------------------------------------------------------------------
// Kernel 2: cast W_out f32 -> bf16
// ---------------------------------------------------------------------------
__global__ void k_cast(const float* __restrict__ src, unsigned short* __restrict__ dst, int n4) {
  int i = blockIdx.x * blockDim.x + threadIdx.x;
  int stride = gridDim.x * blockDim.x;
  for (; i < n4; i += stride) {
    float4 v = ((const float4*)src)[i];
    ushort4 o;
    o.x = f2bf(v.x); o.y = f2bf(v.y); o.z = f2bf(v.z); o.w = f2bf(v.w);
    ((ushort4*)dst)[i] = o;
  }
}

// ---------------------------------------------------------------------------
// Kernel 3: zero the barrier flags (64 ints)
// ---------------------------------------------------------------------------
__global__ void k_zero(int* flags) { flags[threadIdx.x] = 0; }

// ---------------------------------------------------------------------------
// Device-scope flag barrier for 64 co-resident blocks.
// Arrive: per-block release store of `id` to own flag (after __syncthreads:
// every wave's stores are in L2; agent-release writes back L2 -> visible).
// Wait: wave 0 polls all 64 flags (relaxed, coherence-point loads), then
// block-wide acquire fence (invalidates stale lines before h reads).
// ---------------------------------------------------------------------------
__device__ __forceinline__ void gridbar(int* flags, int id) {
  __syncthreads();
  if (threadIdx.x == 0)
    __hip_atomic_store(&flags[blockIdx.x], id, __ATOMIC_RELEASE, __HIP_MEMORY_SCOPE_AGENT);
  if (threadIdx.x < 64) {
    while (__hip_atomic_load(&flags[threadIdx.x], __ATOMIC_RELAXED, __HIP_MEMORY_SCOPE_AGENT) < id)
      __builtin_amdgcn_s_sleep(2);
  }
  __syncthreads();
  __builtin_amdgcn_fence(__ATOMIC_ACQUIRE, "agent");
}

// ---------------------------------------------------------------------------
// Kernel 4: persistent LSTM recurrence (prime + 32 steps, one launch).
// 64 blocks x 256 thr. Block owns u0=bid*8 (8 u x 4 gates). W_hh split to
// bf16 hi/lo ONCE into LDS, gate-packed: frag0 rows = [i(u0..u0+7)|f(...)],
// frag1 = [g|o]; chunk-XOR swizzle for conflict-free ds_read_b128.
// Wave w owns b in [w*16,w*16+16). acc = mfma(h_rows, W_rows): col(lane&15)
// = packed W row (gate,u), row-field = b. c state lives in registers.
// h ping-pongs in global as bf16 hi/lo; barrier between steps via gridbar.
// hall (bf16 hi) stored b-major: row b*32 + (s-1).
// ---------------------------------------------------------------------------
__global__ __launch_bounds__(256) void k_rnn(const float* __restrict__ Gpre,
                                             const float* __restrict__ Whh,
                                             unsigned short* __restrict__ hAhi,
                                             unsigned short* __restrict__ hAlo,
                                             unsigned short* __restrict__ hBhi,
                                             unsigned short* __restrict__ hBlo,
                                             unsigned short* __restrict__ hall,
                                             int* __restrict__ flags) {
  __shared__ __align__(16) unsigned short Wl[2][2][16][512];  // [frag][hi/lo][row][k] = 64 KB
  const int tid = threadIdx.x;
  const int bid = blockIdx.x;
  const int u0 = bid * 8;
  const int l = tid & 63;
  const int w = tid >> 6;
  const int lr = l & 15;
  const int kc = l >> 4;          // 0..3
  const bool lowh = (lr < 8);
  const int u = u0 + (lr & 7);

  // ---- stage W_hh -> LDS (split hi/lo on the fly), 2048 16B-chunk tasks ----
#pragma unroll
  for (int it = 0; it < 8; ++it) {
    int id = it * 256 + tid;        // 0..2047
    int fr = id >> 10;              // frag 0 = gates{i,f}, 1 = {g,o}
    int r = (id >> 6) & 15;         // packed row
    int c = id & 63;                // 16B chunk (8 f32 source elems)
    int gate = fr * 2 + (r >> 3);
    int gr = gate * HH + u0 + (r & 7);
    const float* src = Whh + (size_t)gr * HH + c * 8;
    float4 v0 = *(const float4*)src;
    float4 v1 = *(const float4*)(src + 4);
    float vv[8] = {v0.x, v0.y, v0.z, v0.w, v1.x, v1.y, v1.z, v1.w};
    __align__(16) unsigned short hi8[8];
    __align__(16) unsigned short lo8[8];
#pragma unroll
    for (int e = 0; e < 8; ++e) {
      hi8[e] = f2bf(vv[e]);
      lo8[e] = f2bf(vv[e] - bf2f(hi8[e]));
    }
    int cs = c ^ (r & 7);
    *(int4*)&Wl[fr][0][r][cs * 8] = *(const int4*)hi8;
    *(int4*)&Wl[fr][1][r][cs * 8] = *(const int4*)lo8;
  }

  // ---- prime step (h=c=0): elementwise from Gpre rows 0..63 ----
  float c_reg[4];
#pragma unroll
  for (int j = 0; j < 4; ++j) {
    int b = w * 16 + kc * 4 + j;
    const float* gp = Gpre + (size_t)b * G4;
    float gi = gp[u], gg = gp[1024 + u], go = gp[1536 + u];
    float cn = sigm(gi) * tanh_fast(gg);
    float hn = sigm(go) * tanh_fast(cn);
    c_reg[j] = cn;
    if (lowh) {
      size_t cu = (size_t)b * HH + u;
      unsigned short hb = f2bf(hn);
      hAhi[cu] = hb;
      hAlo[cu] = f2bf(hn - bf2f(hb));
    }
  }
  gridbar(flags, 1);   // also covers LDS staging via its __syncthreads

  // ---- 32 recurrent steps ----
  for (int s = 1; s <= TT; ++s) {
    const unsigned short* hiP = (s & 1) ? hAhi : hBhi;
    const unsigned short* loP = (s & 1) ? hAlo : hBlo;
    unsigned short* hiO = (s & 1) ? hBhi : hAhi;
    unsigned short* loO = (s & 1) ? hBlo : hAlo;

    const f32x4 vz = {0.f, 0.f, 0.f, 0.f};
    f32x4 acc0 = vz, acc1 = vz;
    const size_t a_off = (size_t)(w * 16 + lr) * HH + kc * 8;
#pragma unroll
    for (int t = 0; t < 16; ++t) {
      bf16x8 ah = *(const bf16x8*)(hiP + a_off + t * 32);
      bf16x8 al = *(const bf16x8*)(loP + a_off + t * 32);
      int cs = (t * 4 + kc) ^ (lr & 7);
      bf16x8 b0h = *(const bf16x8*)&Wl[0][0][lr][cs * 8];
      bf16x8 b0l = *(const bf16x8*)&Wl[0][1][lr][cs * 8];
      bf16x8 b1h = *(const bf16x8*)&Wl[1][0][lr][cs * 8];
      bf16x8 b1l = *(const bf16x8*)&Wl[1][1][lr][cs * 8];
      acc0 = __builtin_amdgcn_mfma_f32_16x16x32_bf16(ah, b0h, acc0, 0, 0, 0);
      acc0 = __builtin_amdgcn_mfma_f32_16x16x32_bf16(al, b0h, acc0, 0, 0, 0);
      acc0 = __builtin_amdgcn_mfma_f32_16x16x32_bf16(ah, b0l, acc0, 0, 0, 0);
      acc1 = __builtin_amdgcn_mfma_f32_16x16x32_bf16(ah, b1h, acc1, 0, 0, 0);
      acc1 = __builtin_amdgcn_mfma_f32_16x16x32_bf16(al, b1h, acc1, 0, 0, 0);
      acc1 = __builtin_amdgcn_mfma_f32_16x16x32_bf16(ah, b1l, acc1, 0, 0, 0);
    }

    // epilogue: lane lr holds gate (lr<8 ? i : f) in acc0, (g : o) in acc1
#pragma unroll
    for (int j = 0; j < 4; ++j) {
      int b = w * 16 + kc * 4 + j;
      float my0 = acc0[j], my1 = acc1[j];
      float p0 = __shfl_xor(my0, 8);
      float p1 = __shfl_xor(my1, 8);
      float i_ = lowh ? my0 : p0;
      float f_ = lowh ? p0 : my0;
      float g_ = lowh ? my1 : p1;
      float o_ = lowh ? p1 : my1;
      const float* gp = Gpre + (size_t)(s * 64 + b) * G4;
      i_ += gp[u]; f_ += gp[512 + u]; g_ += gp[1024 + u]; o_ += gp[1536 + u];
      float cn = sigm(f_) * c_reg[j] + sigm(i_) * tanh_fast(g_);
      float hn = sigm(o_) * tanh_fast(cn);
      c_reg[j] = cn;
      if (lowh) {
        size_t cu = (size_t)b * HH + u;
        unsigned short hb = f2bf(hn);
        hiO[cu] = hb;
        loO[cu] = f2bf(hn - bf2f(hb));
        hall[((size_t)b * TT + (s - 1)) * HH + u] = hb;
      }
    }
    if (s < TT) gridbar(flags, s + 1);
  }
}

// ---------------------------------------------------------------------------
// Kernel 5: Out(2048 x 32000) = hall @ W_out.T + b_out  [bf16 MFMA, f32 out]
// (unchanged from round 2 — verified)
// ---------------------------------------------------------------------------
__global__ __launch_bounds__(256) void k_gemm_out(const unsigned short* __restrict__ Xb,
                                                  const unsigned short* __restrict__ Wb,
                                                  const float* __restrict__ bout,
                                                  float* __restrict__ out) {
  __shared__ __align__(16) unsigned short As[128 * 64];
  __shared__ __align__(16) unsigned short Bs[128 * 64];
  const int tid = threadIdx.x;
  int bid = blockIdx.x;
  int swz = (bid & 7) * 500 + (bid >> 3);  // 8 XCDs x 500-block chunks
  const int mt = swz & 15;
  const int nt = swz >> 4;
  const int l = tid & 63;
  const int w = tid >> 6;
  const int wr = (w >> 1) * 64;
  const int wc = (w & 1) * 64;

  const f32x4 vz = {0.f, 0.f, 0.f, 0.f};
  f32x4 acc[4][4];
#pragma unroll
  for (int m = 0; m < 4; m++)
#pragma unroll
    for (int n = 0; n < 4; n++) acc[m][n] = vz;

  const int srow = tid >> 3;
  const int scs = tid & 7;
  const unsigned short* ga0 = Xb + (size_t)(mt * 128) * EE;
  const unsigned short* gb0 = Wb + (size_t)(nt * 128) * EE;

  for (int kt = 0; kt < 8; kt++) {
    if (kt) __syncthreads();
#pragma unroll
    for (int i = 0; i < 4; i++) {
      int row = i * 32 + srow;
      int cb = scs ^ (row & 7);
      gload_lds16(ga0 + (size_t)row * EE + kt * 64 + cb * 8, &As[row * 64 + scs * 8]);
      gload_lds16(gb0 + (size_t)row * EE + kt * 64 + cb * 8, &Bs[row * 64 + scs * 8]);
    }
    __syncthreads();
#pragma unroll
    for (int kk = 0; kk < 2; kk++) {
      bf16x8 af[4], bfr[4];
#pragma unroll
      for (int m = 0; m < 4; m++) {
        int row = wr + m * 16 + (l & 15);
        int cc = kk * 4 + (l >> 4);
        int cs = cc ^ (row & 7);
        af[m] = *(const bf16x8*)&As[row * 64 + cs * 8];
      }
#pragma unroll
      for (int n = 0; n < 4; n++) {
        int row = wc + n * 16 + (l & 15);
        int cc = kk * 4 + (l >> 4);
        int cs = cc ^ (row & 7);
        bfr[n] = *(const bf16x8*)&Bs[row * 64 + cs * 8];
      }
#pragma unroll
      for (int m = 0; m < 4; m++)
#pragma unroll
        for (int n = 0; n < 4; n++)
          acc[m][n] = __builtin_amdgcn_mfma_f32_16x16x32_bf16(bfr[n], af[m], acc[m][n], 0, 0, 0);
    }
  }

  float4 bo4[4];
#pragma unroll
  for (int n = 0; n < 4; n++)
    bo4[n] = *(const float4*)(bout + nt * 128 + wc + n * 16 + (l >> 4) * 4);
#pragma unroll
  for (int m = 0; m < 4; m++) {
    float* orow = out + (size_t)(mt * 128 + wr + m * 16 + (l & 15)) * VV
                      + nt * 128 + wc + (l >> 4) * 4;
#pragma unroll
    for (int n = 0; n < 4; n++) {
      float4 v;
      v.x = acc[m][n][0] + bo4[n].x;
      v.y = acc[m][n][1] + bo4[n].y;
      v.z = acc[m][n][2] + bo4[n].z;
      v.w = acc[m][n][3] + bo4[n].w;
      *(float4*)(orow + n * 16) = v;
    }
  }
}

// ---------------------------------------------------------------------------
extern "C" void kernel_launch(void* const* d_in, const int* in_sizes, int n_in,
                              void* d_out, int out_size, void* d_ws, size_t ws_size,
                              hipStream_t stream) {
  const float* feat = (const float*)d_in[0];
  const int* cap = (const int*)d_in[1];
  // d_in[2] = seq_len (constant 32)
  const float* emb = (const float*)d_in[3];
  const float* Wih = (const float*)d_in[4];
  const float* Whh = (const float*)d_in[5];
  const float* bih = (const float*)d_in[6];
  const float* bhh = (const float*)d_in[7];
  const float* Wout = (const float*)d_in[8];
  const float* bout = (const float*)d_in[9];
  float* out = (float*)d_out;

  char* ws = (char*)d_ws;
  float* Gpre = (float*)ws;                                   // 17,301,504
  unsigned short* hAhi = (unsigned short*)(ws + 17301504);    //     65,536
  unsigned short* hAlo = (unsigned short*)(ws + 17367040);    //     65,536
  unsigned short* hBhi = (unsigned short*)(ws + 17432576);    //     65,536
  unsigned short* hBlo = (unsigned short*)(ws + 17498112);    //     65,536
  unsigned short* hall = (unsigned short*)(ws + 17563648);    //  2,097,152 (b-major)
  unsigned short* Wb = (unsigned short*)(ws + 19660800);      // 32,768,000
  int* flags = (int*)(ws + 52428800);                         //        256

  k_zero<<<dim3(1), dim3(64), 0, stream>>>(flags);
  k_gemm_ih<<<dim3(17 * 16), dim3(256), 0, stream>>>(feat, cap, emb, Wih, bih, bhh, Gpre);
  k_cast<<<dim3(2048), dim3(256), 0, stream>>>(Wout, Wb, (VV * HH) / 4);
  k_rnn<<<dim3(64), dim3(256), 0, stream>>>(Gpre, Whh, hAhi, hAlo, hBhi, hBlo, hall, flags);
  k_gemm_out<<<dim3(4000), dim3(256), 0, stream>>>(hall, Wb, bout, out);
}